// Round 1
// baseline (7077.392 us; speedup 1.0000x reference)
//
#include <hip/hip_runtime.h>

#define CSC 64
#define CVC 32
#define HIDC 128
#define NWC 224
#define RBFD 32
#define CUTF 5.0f

typedef __attribute__((ext_vector_type(8))) short bfrag8;
typedef __attribute__((ext_vector_type(4))) float facc4;

__device__ __forceinline__ unsigned short f2bf(float x) {
    union { float f; unsigned int u; } a; a.f = x;
    unsigned int u = a.u;
    return (unsigned short)((u + 0x7fffu + ((u >> 16) & 1u)) >> 16);
}

__device__ __forceinline__ float siluf(float x) { return x / (1.0f + __expf(-x)); }
__device__ __forceinline__ float sigmf(float x) { return 1.0f / (1.0f + __expf(-x)); }

// ---------------- init: s = (concat(z_emb[z], abs_flag) @ W_in) * mask ; zero v/agg ----------
__global__ __launch_bounds__(128) void eae_init_kernel(
    const int* __restrict__ z, const float* __restrict__ mask, const int* __restrict__ absorber,
    const float* __restrict__ z_emb, const float* __restrict__ W_in,
    float* __restrict__ s, float* __restrict__ v,
    float* __restrict__ aggs, float* __restrict__ aggv)
{
    int n = blockIdx.x;
    int t = threadIdx.x;
    int b = n >> 6;      // N = 64
    int ni = n & 63;
    float fm = mask[n];
    int zi = z[n];
    float af = (absorber[b] == ni) ? 1.0f : 0.0f;
    if (t < 64) {
        const float* ze = z_emb + zi * 64;
        float acc = 0.0f;
        #pragma unroll 4
        for (int k = 0; k < 64; ++k) acc += ze[k] * W_in[k * 64 + t];
        acc += af * W_in[64 * 64 + t];
        s[n * 64 + t] = acc * fm;
    }
    for (int i = t; i < 96; i += 128) { v[n * 96 + i] = 0.0f; aggs[n * 96 + i] = 0.0f; }
    for (int i = t; i < 384; i += 128) aggv[n * 384 + i] = 0.0f;
}

// ---------------- edge kernel: radial MLP (MFMA) + TP messages + atomic scatter --------------
// 256 threads = 4 waves. Tile = 64 edges.
// GEMM1: D1[ch(128) x e(64)] = W1^T (A) * rbf^T (B), K=32
// GEMM2: D2[ch(224->256) x e(64)] = W2^T (A) * h^T (B, from LDS), K=128
__global__ __launch_bounds__(256, 2) void eae_edge_kernel(
    const int* __restrict__ edge_src, const int* __restrict__ edge_dst,
    const float* __restrict__ edge_weight, const float* __restrict__ edge_vec,
    const float* __restrict__ W1b, const float* __restrict__ b1b,
    const float* __restrict__ W2b, const float* __restrict__ b2b,
    const float* __restrict__ s, const float* __restrict__ v,
    float* __restrict__ aggs, float* __restrict__ aggv,
    int E, int ntiles)
{
    __shared__ unsigned short h_lds[64 * 128];   // h[e][k] bf16, swizzled, 16KB
    char* hb = (char*)h_lds;

    const int tid  = threadIdx.x;
    const int wid  = tid >> 6;
    const int lane = tid & 63;
    const int t4   = lane >> 4;
    const int lr   = lane & 15;
    const int swz  = (lr & 7) << 4;   // row e = 16*et+lr -> e&7 == lr&7

    // ---- preload W1^T fragments: ch-tiles {2*wid, 2*wid+1} ----
    bfrag8 a1[2];
    float b1v[2][4];
    #pragma unroll
    for (int m = 0; m < 2; ++m) {
        int mt = 2 * wid + m;
        bfrag8 f;
        #pragma unroll
        for (int i = 0; i < 8; ++i) {
            int k = 8 * t4 + i;
            f[i] = (short)f2bf(W1b[k * HIDC + 16 * mt + lr]);
        }
        a1[m] = f;
        #pragma unroll
        for (int r = 0; r < 4; ++r) b1v[m][r] = b1b[16 * mt + 4 * t4 + r];
    }

    // ---- preload W2^T fragments: ch-tiles {4*wid .. 4*wid+3}, padded to 256 ch ----
    bfrag8 a2[4][4];      // [mtl][ks]
    float b2v[4][4];
    #pragma unroll
    for (int m = 0; m < 4; ++m) {
        int mt = 4 * wid + m;
        int ch = 16 * mt + lr;
        #pragma unroll
        for (int ks = 0; ks < 4; ++ks) {
            bfrag8 f;
            #pragma unroll
            for (int i = 0; i < 8; ++i) {
                int k = 32 * ks + 8 * t4 + i;
                f[i] = (ch < NWC) ? (short)f2bf(W2b[k * NWC + ch]) : (short)0;
            }
            a2[m][ks] = f;
        }
        #pragma unroll
        for (int r = 0; r < 4; ++r) {
            int chr = 16 * mt + 4 * t4 + r;
            b2v[m][r] = (chr < NWC) ? b2b[chr] : 0.0f;
        }
    }

    const float delta = CUTF / (RBFD - 1);
    const float inv_delta = 1.0f / delta;
    const float SQ3 = 1.7320508075688772f;
    const float IS3 = 0.57735026918962576f;
    const float IS2 = 0.70710678118654752f;
    const float PIF = 3.14159265358979323846f;

    for (int tile = blockIdx.x; tile < ntiles; tile += gridDim.x) {
        const int e0 = tile * 64;

        int   src4[4], dst4[4];
        float env4[4], y4[4][3];
        bfrag8 brbf[4];
        #pragma unroll
        for (int et = 0; et < 4; ++et) {
            int eg = e0 + 16 * et + lr;
            bool valid = (eg < E);
            int ee = valid ? eg : 0;
            float el = edge_weight[ee];
            float ex = edge_vec[3 * ee + 0], ey = edge_vec[3 * ee + 1], ez = edge_vec[3 * ee + 2];
            float inv = 1.0f / fmaxf(el, 1e-8f);
            y4[et][0] = SQ3 * ex * inv;
            y4[et][1] = SQ3 * ey * inv;
            y4[et][2] = SQ3 * ez * inv;
            float env = (el < CUTF) ? 0.5f * (__cosf(PIF * el / CUTF) + 1.0f) : 0.0f;
            env4[et] = valid ? env : 0.0f;
            src4[et] = edge_src[ee];
            dst4[et] = edge_dst[ee];
            float d = fminf(el, CUTF);
            bfrag8 f;
            #pragma unroll
            for (int i = 0; i < 8; ++i) {
                int k = 8 * t4 + i;
                float x = (d - (float)k * delta) * inv_delta;
                f[i] = (short)f2bf(__expf(-0.5f * x * x));
            }
            brbf[et] = f;
        }

        // ---- GEMM1 ----
        facc4 acc1[2][4];
        #pragma unroll
        for (int m = 0; m < 2; ++m)
            #pragma unroll
            for (int et = 0; et < 4; ++et) { facc4 zz = {0.f,0.f,0.f,0.f}; acc1[m][et] = zz; }
        #pragma unroll
        for (int et = 0; et < 4; ++et)
            #pragma unroll
            for (int m = 0; m < 2; ++m)
                acc1[m][et] = __builtin_amdgcn_mfma_f32_16x16x32_bf16(a1[m], brbf[et], acc1[m][et], 0, 0, 0);

        // ---- silu -> bf16 -> LDS h[e][ch], XOR-swizzled 16B slots ----
        #pragma unroll
        for (int m = 0; m < 2; ++m) {
            int ch0b = (16 * (2 * wid + m) + 4 * t4) * 2;   // byte offset in row
            #pragma unroll
            for (int et = 0; et < 4; ++et) {
                int e = 16 * et + lr;
                unsigned short hv[4];
                #pragma unroll
                for (int r = 0; r < 4; ++r) {
                    float x = acc1[m][et][r] + b1v[m][r];
                    hv[r] = f2bf(siluf(x));
                }
                uint2 pk;
                pk.x = (unsigned int)hv[0] | ((unsigned int)hv[1] << 16);
                pk.y = (unsigned int)hv[2] | ((unsigned int)hv[3] << 16);
                *reinterpret_cast<uint2*>(hb + e * 256 + (ch0b ^ swz)) = pk;
            }
        }
        __syncthreads();

        // ---- GEMM2 ----
        facc4 acc2[4][4];
        #pragma unroll
        for (int m = 0; m < 4; ++m)
            #pragma unroll
            for (int et = 0; et < 4; ++et) { facc4 zz = {0.f,0.f,0.f,0.f}; acc2[m][et] = zz; }
        #pragma unroll
        for (int et = 0; et < 4; ++et) {
            int e = 16 * et + lr;
            bfrag8 hf[4];
            #pragma unroll
            for (int ks = 0; ks < 4; ++ks)
                hf[ks] = *reinterpret_cast<const bfrag8*>(hb + e * 256 + ((64 * ks + 16 * t4) ^ swz));
            #pragma unroll
            for (int m = 0; m < 4; ++m)
                #pragma unroll
                for (int ks = 0; ks < 4; ++ks)
                    acc2[m][et] = __builtin_amdgcn_mfma_f32_16x16x32_bf16(a2[m][ks], hf[ks], acc2[m][et], 0, 0, 0);
        }

        // ---- epilogue: w = (acc + b2)*env; tensor-product messages; atomic scatter ----
        #pragma unroll
        for (int m = 0; m < 4; ++m) {
            int mt = 4 * wid + m;          // 0..15 (14,15 are padding)
            if (mt >= 14) continue;
            #pragma unroll
            for (int et = 0; et < 4; ++et) {
                int src = src4[et], dst = dst4[et];
                float env = env4[et];
                float w[4];
                #pragma unroll
                for (int r = 0; r < 4; ++r) w[r] = (acc2[m][et][r] + b2v[m][r]) * env;
                float yx = y4[et][0], yy = y4[et][1], yz = y4[et][2];

                if (mt < 4) {               // w_ss: 0e x 0e -> 0e
                    int c0 = 16 * mt + 4 * t4;
                    const float4 sv = *reinterpret_cast<const float4*>(&s[src * CSC + c0]);
                    float vals[4] = {sv.x, sv.y, sv.z, sv.w};
                    #pragma unroll
                    for (int r = 0; r < 4; ++r)
                        atomicAdd(&aggs[dst * 96 + c0 + r], w[r] * vals[r]);
                } else if (mt < 6) {        // w_vv: 1o x 1o -> 0e
                    int c0 = 16 * (mt - 4) + 4 * t4;
                    #pragma unroll
                    for (int r = 0; r < 4; ++r) {
                        int c = c0 + r;
                        const float* vp = &v[src * 96 + c * 3];
                        float dp = vp[0] * yx + vp[1] * yy + vp[2] * yz;
                        atomicAdd(&aggs[dst * 96 + 64 + c], w[r] * dp * IS3);
                    }
                } else if (mt < 10) {       // w_sv: 0e x 1o -> 1o
                    int c0 = 16 * (mt - 6) + 4 * t4;
                    const float4 sv = *reinterpret_cast<const float4*>(&s[src * CSC + c0]);
                    float vals[4] = {sv.x, sv.y, sv.z, sv.w};
                    #pragma unroll
                    for (int r = 0; r < 4; ++r) {
                        float wv = w[r] * vals[r];
                        atomicAdd(&aggv[dst * 384 + (c0 + r) * 3 + 0], wv * yx);
                        atomicAdd(&aggv[dst * 384 + (c0 + r) * 3 + 1], wv * yy);
                        atomicAdd(&aggv[dst * 384 + (c0 + r) * 3 + 2], wv * yz);
                    }
                } else if (mt < 12) {       // w_vs: 1o x 0e -> 1o
                    int c0 = 16 * (mt - 10) + 4 * t4;
                    #pragma unroll
                    for (int r = 0; r < 4; ++r) {
                        int c = c0 + r;
                        const float* vp = &v[src * 96 + c * 3];
                        atomicAdd(&aggv[dst * 384 + (64 + c) * 3 + 0], w[r] * vp[0]);
                        atomicAdd(&aggv[dst * 384 + (64 + c) * 3 + 1], w[r] * vp[1]);
                        atomicAdd(&aggv[dst * 384 + (64 + c) * 3 + 2], w[r] * vp[2]);
                    }
                } else {                    // w_vx: 1o x 1o -> 1o (cross)
                    int c0 = 16 * (mt - 12) + 4 * t4;
                    #pragma unroll
                    for (int r = 0; r < 4; ++r) {
                        int c = c0 + r;
                        const float* vp = &v[src * 96 + c * 3];
                        float ax = vp[0], ay = vp[1], az = vp[2];
                        float cx = ay * yz - az * yy;
                        float cy = az * yx - ax * yz;
                        float cz = ax * yy - ay * yx;
                        float ww = w[r] * IS2;
                        atomicAdd(&aggv[dst * 384 + (96 + c) * 3 + 0], ww * cx);
                        atomicAdd(&aggv[dst * 384 + (96 + c) * 3 + 1], ww * cy);
                        atomicAdd(&aggv[dst * 384 + (96 + c) * 3 + 2], ww * cz);
                    }
                }
            }
        }
        __syncthreads();   // protect h_lds before next tile's writes
    }
}

// ---------------- node update: us/uv/g + residual; zero agg for next block --------------------
__global__ __launch_bounds__(128) void eae_node_kernel(
    const float* __restrict__ Ws, const float* __restrict__ Wv, const float* __restrict__ Wg,
    const float* __restrict__ alpha,
    float* __restrict__ s, float* __restrict__ v,
    float* __restrict__ aggs, float* __restrict__ aggv, int blk)
{
    int n = blockIdx.x;
    int t = threadIdx.x;
    __shared__ float sh_as[96];
    __shared__ float sh_av[384];
    __shared__ float sh_us[64];
    __shared__ float sh_g[32];

    for (int i = t; i < 96; i += 128) sh_as[i] = aggs[n * 96 + i];
    for (int i = t; i < 384; i += 128) sh_av[i] = aggv[n * 384 + i];
    __syncthreads();

    float a = alpha[blk];
    const float* Wsb = Ws + blk * 96 * 64;
    const float* Wvb = Wv + blk * 128 * 32;
    const float* Wgb = Wg + blk * 64 * 32;

    if (t < 64) {
        float acc = 0.0f;
        #pragma unroll 4
        for (int j = 0; j < 96; ++j) acc += sh_as[j] * Wsb[j * 64 + t];
        sh_us[t] = siluf(acc);
    }
    __syncthreads();
    if (t < 32) {
        float acc = 0.0f;
        #pragma unroll 4
        for (int j = 0; j < 64; ++j) acc += sh_us[j] * Wgb[j * 32 + t];
        sh_g[t] = sigmf(acc);
    }
    if (t < 64) s[n * 64 + t] += a * sh_us[t];
    __syncthreads();
    if (t < 96) {
        int c = t / 3;
        int d = t - 3 * c;
        float acc = 0.0f;
        #pragma unroll 4
        for (int j = 0; j < 128; ++j) acc += sh_av[j * 3 + d] * Wvb[j * 32 + c];
        v[n * 96 + t] += a * sh_g[c] * acc;
    }
    // zero agg for next block iteration
    for (int i = t; i < 96; i += 128) aggs[n * 96 + i] = 0.0f;
    for (int i = t; i < 384; i += 128) aggv[n * 384 + i] = 0.0f;
}

// ---------------- final: IrrepNorm + mask + pack output ------------------------------------
__global__ __launch_bounds__(64) void eae_final_kernel(
    const float* __restrict__ mask, const float* __restrict__ s, const float* __restrict__ v,
    float* __restrict__ out)
{
    int n = blockIdx.x;
    int t = threadIdx.x;
    float fm = mask[n];

    float sv = s[n * 64 + t];
    float ss = sv * sv;
    #pragma unroll
    for (int o = 32; o >= 1; o >>= 1) ss += __shfl_xor(ss, o);
    float sn = sv / sqrtf(ss / 64.0f + 1e-6f);
    out[n * 160 + t] = sn * fm;

    float v0 = v[n * 96 + t];
    float v1 = (t < 32) ? v[n * 96 + 64 + t] : 0.0f;
    float vs2 = v0 * v0 + v1 * v1;
    #pragma unroll
    for (int o = 32; o >= 1; o >>= 1) vs2 += __shfl_xor(vs2, o);
    float scale = fm / sqrtf(vs2 / 32.0f + 1e-6f);
    out[n * 160 + 64 + t] = v0 * scale;
    if (t < 32) out[n * 160 + 128 + t] = v1 * scale;
}

extern "C" void kernel_launch(void* const* d_in, const int* in_sizes, int n_in,
                              void* d_out, int out_size, void* d_ws, size_t ws_size,
                              hipStream_t stream) {
    const int*   z           = (const int*)d_in[0];
    const float* mask        = (const float*)d_in[1];
    const int*   absorber    = (const int*)d_in[2];
    const int*   edge_src    = (const int*)d_in[3];
    const int*   edge_dst    = (const int*)d_in[4];
    const float* edge_weight = (const float*)d_in[5];
    const float* edge_vec    = (const float*)d_in[6];
    const float* z_emb       = (const float*)d_in[7];
    const float* W_in        = (const float*)d_in[8];
    const float* W1          = (const float*)d_in[9];
    const float* b1          = (const float*)d_in[10];
    const float* W2          = (const float*)d_in[11];
    const float* b2          = (const float*)d_in[12];
    const float* Ws          = (const float*)d_in[13];
    const float* Wv          = (const float*)d_in[14];
    const float* Wg          = (const float*)d_in[15];
    const float* alpha       = (const float*)d_in[16];
    float* out = (float*)d_out;

    const int BN = in_sizes[0];    // B*N = 2048
    const int E  = in_sizes[3];    // 131072

    float* ws_f = (float*)d_ws;
    float* s    = ws_f;                  // BN*64
    float* v    = s + (size_t)BN * 64;   // BN*96
    float* aggs = v + (size_t)BN * 96;   // BN*96
    float* aggv = aggs + (size_t)BN * 96;// BN*384

    eae_init_kernel<<<BN, 128, 0, stream>>>(z, mask, absorber, z_emb, W_in, s, v, aggs, aggv);

    int ntiles = (E + 63) / 64;
    int grid = ntiles < 512 ? ntiles : 512;
    for (int blk = 0; blk < 3; ++blk) {
        eae_edge_kernel<<<grid, 256, 0, stream>>>(
            edge_src, edge_dst, edge_weight, edge_vec,
            W1 + (size_t)blk * 32 * 128, b1 + (size_t)blk * 128,
            W2 + (size_t)blk * 128 * 224, b2 + (size_t)blk * 224,
            s, v, aggs, aggv, E, ntiles);
        eae_node_kernel<<<BN, 128, 0, stream>>>(Ws, Wv, Wg, alpha, s, v, aggs, aggv, blk);
    }
    eae_final_kernel<<<BN, 64, 0, stream>>>(mask, s, v, out);
}

// Round 2
// 639.224 us; speedup vs baseline: 11.0718x; 11.0718x over previous
//
#include <hip/hip_runtime.h>

#define CSC 64
#define CVC 32
#define HIDC 128
#define NWC 224
#define RBFD 32
#define CUTF 5.0f

typedef __attribute__((ext_vector_type(8))) short bfrag8;
typedef __attribute__((ext_vector_type(4))) float facc4;

__device__ __forceinline__ unsigned short f2bf(float x) {
    union { float f; unsigned int u; } a; a.f = x;
    unsigned int u = a.u;
    return (unsigned short)((u + 0x7fffu + ((u >> 16) & 1u)) >> 16);
}

__device__ __forceinline__ float siluf(float x) { return x / (1.0f + __expf(-x)); }
__device__ __forceinline__ float sigmf(float x) { return 1.0f / (1.0f + __expf(-x)); }

// ---------------- CSR build: histogram -> scan -> scatter-permute ---------------------------
__global__ __launch_bounds__(256) void eae_zero_int(int* __restrict__ p, int n) {
    int i = blockIdx.x * 256 + threadIdx.x;
    if (i < n) p[i] = 0;
}

__global__ __launch_bounds__(256) void eae_hist_kernel(const int* __restrict__ edge_dst,
                                                       int* __restrict__ cnt, int E) {
    int e = blockIdx.x * 256 + threadIdx.x;
    if (e < E) atomicAdd(&cnt[edge_dst[e]], 1);
}

__global__ __launch_bounds__(256) void eae_scan_kernel(const int* __restrict__ cnt,
                                                       int* __restrict__ row_ptr,
                                                       int* __restrict__ cursor, int BN) {
    __shared__ int part[256];
    int t = threadIdx.x;
    int per = (BN + 255) / 256;           // 8 for BN=2048
    int base = t * per;
    int local[16];
    int lsum = 0;
    for (int i = 0; i < per; ++i) {
        int idx = base + i;
        int c = (idx < BN) ? cnt[idx] : 0;
        local[i] = c; lsum += c;
    }
    part[t] = lsum;
    __syncthreads();
    if (t == 0) {
        int run = 0;
        for (int i = 0; i < 256; ++i) { int v = part[i]; part[i] = run; run += v; }
    }
    __syncthreads();
    int run = part[t];
    for (int i = 0; i < per; ++i) {
        int idx = base + i;
        if (idx < BN) { row_ptr[idx] = run; cursor[idx] = run; run += local[i]; }
    }
    if (t == 255) row_ptr[BN] = run;
}

__global__ __launch_bounds__(256) void eae_scatter_kernel(const int* __restrict__ edge_dst,
                                                          int* __restrict__ cursor,
                                                          int* __restrict__ perm, int E) {
    int e = blockIdx.x * 256 + threadIdx.x;
    if (e < E) {
        int pos = atomicAdd(&cursor[edge_dst[e]], 1);
        perm[pos] = e;
    }
}

// ---------------- init: s = (concat(z_emb[z], abs_flag) @ W_in) * mask ; zero v --------------
__global__ __launch_bounds__(128) void eae_init_kernel(
    const int* __restrict__ z, const float* __restrict__ mask, const int* __restrict__ absorber,
    const float* __restrict__ z_emb, const float* __restrict__ W_in,
    float* __restrict__ s, float* __restrict__ v)
{
    int n = blockIdx.x;
    int t = threadIdx.x;
    int b = n >> 6;      // N = 64
    int ni = n & 63;
    float fm = mask[n];
    int zi = z[n];
    float af = (absorber[b] == ni) ? 1.0f : 0.0f;
    if (t < 64) {
        const float* ze = z_emb + zi * 64;
        float acc = 0.0f;
        #pragma unroll 4
        for (int k = 0; k < 64; ++k) acc += ze[k] * W_in[k * 64 + t];
        acc += af * W_in[64 * 64 + t];
        s[n * 64 + t] = acc * fm;
    }
    for (int i = t; i < 96; i += 128) v[n * 96 + i] = 0.0f;
}

// ---------------- edge kernel: per-dst gather, radial MLP (MFMA) + TP + shuffle-reduce -------
// 256 threads = 4 waves. One destination node at a time; 64-edge tiles from CSR perm list.
// GEMM1: D1[ch(128) x e(64)] = W1^T (A) * rbf^T (B), K=32
// GEMM2: D2[ch(224->256) x e(64)] = W2^T (A) * h^T (B, from LDS), K=128
__global__ __launch_bounds__(256, 2) void eae_edge_kernel(
    const int* __restrict__ perm, const int* __restrict__ row_ptr,
    const int* __restrict__ edge_src,
    const float* __restrict__ edge_weight, const float* __restrict__ edge_vec,
    const float* __restrict__ W1b, const float* __restrict__ b1b,
    const float* __restrict__ W2b, const float* __restrict__ b2b,
    const float* __restrict__ s, const float* __restrict__ v,
    float* __restrict__ aggs, float* __restrict__ aggv, int BN)
{
    __shared__ unsigned short h_lds[64 * 128];   // h[e][k] bf16, swizzled, 16KB
    char* hb = (char*)h_lds;

    const int tid  = threadIdx.x;
    const int wid  = tid >> 6;
    const int lane = tid & 63;
    const int t4   = lane >> 4;
    const int lr   = lane & 15;
    const int swz  = (lr & 7) << 4;

    // ---- preload W1^T fragments: ch-tiles {2*wid, 2*wid+1} ----
    bfrag8 a1[2];
    float b1v[2][4];
    #pragma unroll
    for (int m = 0; m < 2; ++m) {
        int mt = 2 * wid + m;
        bfrag8 f;
        #pragma unroll
        for (int i = 0; i < 8; ++i) {
            int k = 8 * t4 + i;
            f[i] = (short)f2bf(W1b[k * HIDC + 16 * mt + lr]);
        }
        a1[m] = f;
        #pragma unroll
        for (int r = 0; r < 4; ++r) b1v[m][r] = b1b[16 * mt + 4 * t4 + r];
    }

    // ---- preload W2^T fragments: ch-tiles {4*wid .. 4*wid+3}, padded to 256 ch ----
    bfrag8 a2[4][4];      // [mtl][ks]
    float b2v[4][4];
    #pragma unroll
    for (int m = 0; m < 4; ++m) {
        int mt = 4 * wid + m;
        int ch = 16 * mt + lr;
        #pragma unroll
        for (int ks = 0; ks < 4; ++ks) {
            bfrag8 f;
            #pragma unroll
            for (int i = 0; i < 8; ++i) {
                int k = 32 * ks + 8 * t4 + i;
                f[i] = (ch < NWC) ? (short)f2bf(W2b[k * NWC + ch]) : (short)0;
            }
            a2[m][ks] = f;
        }
        #pragma unroll
        for (int r = 0; r < 4; ++r) {
            int chr = 16 * mt + 4 * t4 + r;
            b2v[m][r] = (chr < NWC) ? b2b[chr] : 0.0f;
        }
    }

    const float delta = CUTF / (RBFD - 1);
    const float inv_delta = 1.0f / delta;
    const float SQ3 = 1.7320508075688772f;
    const float IS3 = 0.57735026918962576f;
    const float IS2 = 0.70710678118654752f;
    const float PIF = 3.14159265358979323846f;

    for (int n = blockIdx.x; n < BN; n += gridDim.x) {
        const int ebeg = row_ptr[n];
        const int ecnt = row_ptr[n + 1] - ebeg;
        const int ntile = (ecnt + 63) >> 6;

        float rA[4][4][3];   // per-m channel accumulators (valid on all lanes post-butterfly)
        #pragma unroll
        for (int m = 0; m < 4; ++m)
            #pragma unroll
            for (int r = 0; r < 4; ++r)
                #pragma unroll
                for (int c = 0; c < 3; ++c) rA[m][r][c] = 0.0f;

        for (int tile = 0; tile < ntile; ++tile) {
            const int e0 = tile * 64;

            int   src4[4];
            float env4[4], y4[4][3];
            bfrag8 brbf[4];
            #pragma unroll
            for (int et = 0; et < 4; ++et) {
                int el_idx = e0 + 16 * et + lr;
                bool valid = (el_idx < ecnt);
                int ee = perm[ebeg + (valid ? el_idx : 0)];
                float el = edge_weight[ee];
                float ex = edge_vec[3 * ee + 0], ey = edge_vec[3 * ee + 1], ez = edge_vec[3 * ee + 2];
                float inv = 1.0f / fmaxf(el, 1e-8f);
                y4[et][0] = SQ3 * ex * inv;
                y4[et][1] = SQ3 * ey * inv;
                y4[et][2] = SQ3 * ez * inv;
                float env = (el < CUTF) ? 0.5f * (__cosf(PIF * el / CUTF) + 1.0f) : 0.0f;
                env4[et] = valid ? env : 0.0f;
                src4[et] = edge_src[ee];
                float d = fminf(el, CUTF);
                bfrag8 f;
                #pragma unroll
                for (int i = 0; i < 8; ++i) {
                    int k = 8 * t4 + i;
                    float x = (d - (float)k * delta) * inv_delta;
                    f[i] = (short)f2bf(__expf(-0.5f * x * x));
                }
                brbf[et] = f;
            }

            // ---- GEMM1 ----
            facc4 acc1[2][4];
            #pragma unroll
            for (int m = 0; m < 2; ++m)
                #pragma unroll
                for (int et = 0; et < 4; ++et) { facc4 zz = {0.f,0.f,0.f,0.f}; acc1[m][et] = zz; }
            #pragma unroll
            for (int et = 0; et < 4; ++et)
                #pragma unroll
                for (int m = 0; m < 2; ++m)
                    acc1[m][et] = __builtin_amdgcn_mfma_f32_16x16x32_bf16(a1[m], brbf[et], acc1[m][et], 0, 0, 0);

            // ---- silu -> bf16 -> LDS h[e][ch], XOR-swizzled 16B slots ----
            #pragma unroll
            for (int m = 0; m < 2; ++m) {
                int ch0b = (16 * (2 * wid + m) + 4 * t4) * 2;
                #pragma unroll
                for (int et = 0; et < 4; ++et) {
                    int e = 16 * et + lr;
                    unsigned short hv[4];
                    #pragma unroll
                    for (int r = 0; r < 4; ++r) {
                        float x = acc1[m][et][r] + b1v[m][r];
                        hv[r] = f2bf(siluf(x));
                    }
                    uint2 pk;
                    pk.x = (unsigned int)hv[0] | ((unsigned int)hv[1] << 16);
                    pk.y = (unsigned int)hv[2] | ((unsigned int)hv[3] << 16);
                    *reinterpret_cast<uint2*>(hb + e * 256 + (ch0b ^ swz)) = pk;
                }
            }
            __syncthreads();

            // ---- GEMM2 ----
            facc4 acc2[4][4];
            #pragma unroll
            for (int m = 0; m < 4; ++m)
                #pragma unroll
                for (int et = 0; et < 4; ++et) { facc4 zz = {0.f,0.f,0.f,0.f}; acc2[m][et] = zz; }
            #pragma unroll
            for (int et = 0; et < 4; ++et) {
                int e = 16 * et + lr;
                bfrag8 hf[4];
                #pragma unroll
                for (int ks = 0; ks < 4; ++ks)
                    hf[ks] = *reinterpret_cast<const bfrag8*>(hb + e * 256 + ((64 * ks + 16 * t4) ^ swz));
                #pragma unroll
                for (int m = 0; m < 4; ++m)
                    #pragma unroll
                    for (int ks = 0; ks < 4; ++ks)
                        acc2[m][et] = __builtin_amdgcn_mfma_f32_16x16x32_bf16(a2[m][ks], hf[ks], acc2[m][et], 0, 0, 0);
            }

            // ---- epilogue: messages for this dst; sum over et in-reg, over lr via butterfly ----
            #pragma unroll
            for (int m = 0; m < 4; ++m) {
                int mt = 4 * wid + m;
                if (mt < 14) {
                    float tmp[4][3];
                    #pragma unroll
                    for (int r = 0; r < 4; ++r)
                        #pragma unroll
                        for (int c = 0; c < 3; ++c) tmp[r][c] = 0.0f;

                    if (mt < 4) {               // w_ss
                        int c0 = 16 * mt + 4 * t4;
                        #pragma unroll
                        for (int et = 0; et < 4; ++et) {
                            int src = src4[et]; float env = env4[et];
                            const float4 sv = *reinterpret_cast<const float4*>(&s[src * CSC + c0]);
                            float vals[4] = {sv.x, sv.y, sv.z, sv.w};
                            #pragma unroll
                            for (int r = 0; r < 4; ++r) {
                                float w = (acc2[m][et][r] + b2v[m][r]) * env;
                                tmp[r][0] += w * vals[r];
                            }
                        }
                    } else if (mt < 6) {        // w_vv
                        int c0 = 16 * (mt - 4) + 4 * t4;
                        #pragma unroll
                        for (int et = 0; et < 4; ++et) {
                            int src = src4[et]; float env = env4[et];
                            float yx = y4[et][0], yy = y4[et][1], yz = y4[et][2];
                            #pragma unroll
                            for (int r = 0; r < 4; ++r) {
                                const float* vp = &v[src * 96 + (c0 + r) * 3];
                                float dp = vp[0] * yx + vp[1] * yy + vp[2] * yz;
                                float w = (acc2[m][et][r] + b2v[m][r]) * env;
                                tmp[r][0] += w * dp * IS3;
                            }
                        }
                    } else if (mt < 10) {       // w_sv
                        int c0 = 16 * (mt - 6) + 4 * t4;
                        #pragma unroll
                        for (int et = 0; et < 4; ++et) {
                            int src = src4[et]; float env = env4[et];
                            float yx = y4[et][0], yy = y4[et][1], yz = y4[et][2];
                            const float4 sv = *reinterpret_cast<const float4*>(&s[src * CSC + c0]);
                            float vals[4] = {sv.x, sv.y, sv.z, sv.w};
                            #pragma unroll
                            for (int r = 0; r < 4; ++r) {
                                float wv = (acc2[m][et][r] + b2v[m][r]) * env * vals[r];
                                tmp[r][0] += wv * yx;
                                tmp[r][1] += wv * yy;
                                tmp[r][2] += wv * yz;
                            }
                        }
                    } else if (mt < 12) {       // w_vs
                        int c0 = 16 * (mt - 10) + 4 * t4;
                        #pragma unroll
                        for (int et = 0; et < 4; ++et) {
                            int src = src4[et]; float env = env4[et];
                            #pragma unroll
                            for (int r = 0; r < 4; ++r) {
                                const float* vp = &v[src * 96 + (c0 + r) * 3];
                                float w = (acc2[m][et][r] + b2v[m][r]) * env;
                                tmp[r][0] += w * vp[0];
                                tmp[r][1] += w * vp[1];
                                tmp[r][2] += w * vp[2];
                            }
                        }
                    } else {                    // w_vx (cross)
                        int c0 = 16 * (mt - 12) + 4 * t4;
                        #pragma unroll
                        for (int et = 0; et < 4; ++et) {
                            int src = src4[et]; float env = env4[et];
                            float yx = y4[et][0], yy = y4[et][1], yz = y4[et][2];
                            #pragma unroll
                            for (int r = 0; r < 4; ++r) {
                                const float* vp = &v[src * 96 + (c0 + r) * 3];
                                float ax = vp[0], ay = vp[1], az = vp[2];
                                float ww = (acc2[m][et][r] + b2v[m][r]) * env * IS2;
                                tmp[r][0] += ww * (ay * yz - az * yy);
                                tmp[r][1] += ww * (az * yx - ax * yz);
                                tmp[r][2] += ww * (ax * yy - ay * yx);
                            }
                        }
                    }

                    #pragma unroll
                    for (int r = 0; r < 4; ++r)
                        #pragma unroll
                        for (int c = 0; c < 3; ++c) {
                            float x = tmp[r][c];
                            x += __shfl_xor(x, 1);
                            x += __shfl_xor(x, 2);
                            x += __shfl_xor(x, 4);
                            x += __shfl_xor(x, 8);
                            rA[m][r][c] += x;
                        }
                }
            }
            __syncthreads();   // protect h_lds before next tile's writes
        }

        // ---- store this node's aggregates (each channel owned by one (wid,t4,r)) ----
        if (lr == 0) {
            #pragma unroll
            for (int m = 0; m < 4; ++m) {
                int mt = 4 * wid + m;
                if (mt < 4) {
                    int c0 = 16 * mt + 4 * t4;
                    #pragma unroll
                    for (int r = 0; r < 4; ++r) aggs[n * 96 + c0 + r] = rA[m][r][0];
                } else if (mt < 6) {
                    int c0 = 16 * (mt - 4) + 4 * t4;
                    #pragma unroll
                    for (int r = 0; r < 4; ++r) aggs[n * 96 + 64 + c0 + r] = rA[m][r][0];
                } else if (mt < 10) {
                    int c0 = 16 * (mt - 6) + 4 * t4;
                    #pragma unroll
                    for (int r = 0; r < 4; ++r)
                        #pragma unroll
                        for (int c = 0; c < 3; ++c)
                            aggv[n * 384 + (c0 + r) * 3 + c] = rA[m][r][c];
                } else if (mt < 12) {
                    int c0 = 16 * (mt - 10) + 4 * t4;
                    #pragma unroll
                    for (int r = 0; r < 4; ++r)
                        #pragma unroll
                        for (int c = 0; c < 3; ++c)
                            aggv[n * 384 + (64 + c0 + r) * 3 + c] = rA[m][r][c];
                } else if (mt < 14) {
                    int c0 = 16 * (mt - 12) + 4 * t4;
                    #pragma unroll
                    for (int r = 0; r < 4; ++r)
                        #pragma unroll
                        for (int c = 0; c < 3; ++c)
                            aggv[n * 384 + (96 + c0 + r) * 3 + c] = rA[m][r][c];
                }
            }
        }
    }
}

// ---------------- node update: us/uv/g + residual ------------------------------------------
__global__ __launch_bounds__(128) void eae_node_kernel(
    const float* __restrict__ Ws, const float* __restrict__ Wv, const float* __restrict__ Wg,
    const float* __restrict__ alpha,
    float* __restrict__ s, float* __restrict__ v,
    const float* __restrict__ aggs, const float* __restrict__ aggv, int blk)
{
    int n = blockIdx.x;
    int t = threadIdx.x;
    __shared__ float sh_as[96];
    __shared__ float sh_av[384];
    __shared__ float sh_us[64];
    __shared__ float sh_g[32];

    for (int i = t; i < 96; i += 128) sh_as[i] = aggs[n * 96 + i];
    for (int i = t; i < 384; i += 128) sh_av[i] = aggv[n * 384 + i];
    __syncthreads();

    float a = alpha[blk];
    const float* Wsb = Ws + blk * 96 * 64;
    const float* Wvb = Wv + blk * 128 * 32;
    const float* Wgb = Wg + blk * 64 * 32;

    if (t < 64) {
        float acc = 0.0f;
        #pragma unroll 4
        for (int j = 0; j < 96; ++j) acc += sh_as[j] * Wsb[j * 64 + t];
        sh_us[t] = siluf(acc);
    }
    __syncthreads();
    if (t < 32) {
        float acc = 0.0f;
        #pragma unroll 4
        for (int j = 0; j < 64; ++j) acc += sh_us[j] * Wgb[j * 32 + t];
        sh_g[t] = sigmf(acc);
    }
    if (t < 64) s[n * 64 + t] += a * sh_us[t];
    __syncthreads();
    if (t < 96) {
        int c = t / 3;
        int d = t - 3 * c;
        float acc = 0.0f;
        #pragma unroll 4
        for (int j = 0; j < 128; ++j) acc += sh_av[j * 3 + d] * Wvb[j * 32 + c];
        v[n * 96 + t] += a * sh_g[c] * acc;
    }
}

// ---------------- final: IrrepNorm + mask + pack output ------------------------------------
__global__ __launch_bounds__(64) void eae_final_kernel(
    const float* __restrict__ mask, const float* __restrict__ s, const float* __restrict__ v,
    float* __restrict__ out)
{
    int n = blockIdx.x;
    int t = threadIdx.x;
    float fm = mask[n];

    float sv = s[n * 64 + t];
    float ss = sv * sv;
    #pragma unroll
    for (int o = 32; o >= 1; o >>= 1) ss += __shfl_xor(ss, o);
    float sn = sv / sqrtf(ss / 64.0f + 1e-6f);
    out[n * 160 + t] = sn * fm;

    float v0 = v[n * 96 + t];
    float v1 = (t < 32) ? v[n * 96 + 64 + t] : 0.0f;
    float vs2 = v0 * v0 + v1 * v1;
    #pragma unroll
    for (int o = 32; o >= 1; o >>= 1) vs2 += __shfl_xor(vs2, o);
    float scale = fm / sqrtf(vs2 / 32.0f + 1e-6f);
    out[n * 160 + 64 + t] = v0 * scale;
    if (t < 32) out[n * 160 + 128 + t] = v1 * scale;
}

extern "C" void kernel_launch(void* const* d_in, const int* in_sizes, int n_in,
                              void* d_out, int out_size, void* d_ws, size_t ws_size,
                              hipStream_t stream) {
    const int*   z           = (const int*)d_in[0];
    const float* mask        = (const float*)d_in[1];
    const int*   absorber    = (const int*)d_in[2];
    const int*   edge_src    = (const int*)d_in[3];
    const int*   edge_dst    = (const int*)d_in[4];
    const float* edge_weight = (const float*)d_in[5];
    const float* edge_vec    = (const float*)d_in[6];
    const float* z_emb       = (const float*)d_in[7];
    const float* W_in        = (const float*)d_in[8];
    const float* W1          = (const float*)d_in[9];
    const float* b1          = (const float*)d_in[10];
    const float* W2          = (const float*)d_in[11];
    const float* b2          = (const float*)d_in[12];
    const float* Ws          = (const float*)d_in[13];
    const float* Wv          = (const float*)d_in[14];
    const float* Wg          = (const float*)d_in[15];
    const float* alpha       = (const float*)d_in[16];
    float* out = (float*)d_out;

    const int BN = in_sizes[0];    // B*N = 2048
    const int E  = in_sizes[3];    // 131072

    float* ws_f = (float*)d_ws;
    float* s    = ws_f;                   // BN*64
    float* v    = s + (size_t)BN * 64;    // BN*96
    float* aggs = v + (size_t)BN * 96;    // BN*96
    float* aggv = aggs + (size_t)BN * 96; // BN*384
    int*   iws  = (int*)(aggv + (size_t)BN * 384);
    int* cnt     = iws;                   // BN
    int* row_ptr = cnt + BN;              // BN+1
    int* cursor  = row_ptr + BN + 1;      // BN
    int* perm    = cursor + BN;           // E

    // ---- CSR build (per call; edges static within a call) ----
    eae_zero_int<<<(BN + 255) / 256, 256, 0, stream>>>(cnt, BN);
    eae_hist_kernel<<<(E + 255) / 256, 256, 0, stream>>>(edge_dst, cnt, E);
    eae_scan_kernel<<<1, 256, 0, stream>>>(cnt, row_ptr, cursor, BN);
    eae_scatter_kernel<<<(E + 255) / 256, 256, 0, stream>>>(edge_dst, cursor, perm, E);

    eae_init_kernel<<<BN, 128, 0, stream>>>(z, mask, absorber, z_emb, W_in, s, v);

    for (int blk = 0; blk < 3; ++blk) {
        eae_edge_kernel<<<512, 256, 0, stream>>>(
            perm, row_ptr, edge_src, edge_weight, edge_vec,
            W1 + (size_t)blk * 32 * 128, b1 + (size_t)blk * 128,
            W2 + (size_t)blk * 128 * 224, b2 + (size_t)blk * 224,
            s, v, aggs, aggv, BN);
        eae_node_kernel<<<BN, 128, 0, stream>>>(Ws, Wv, Wg, alpha, s, v, aggs, aggv, blk);
    }
    eae_final_kernel<<<BN, 64, 0, stream>>>(mask, s, v, out);
}